// Round 1
// baseline (902.140 us; speedup 1.0000x reference)
//
#include <hip/hip_runtime.h>
#include <cstdint>
#include <cstddef>

#define NEG_SLOPE 0.2f

static __device__ __forceinline__ float leaky(float v) { return v > 0.f ? v : NEG_SLOPE * v; }

// ---------------- CSR construction ----------------

__global__ void hist_kernel(const int* __restrict__ dst, int E, int Etot,
                            int* __restrict__ counts) {
    int i = blockIdx.x * blockDim.x + threadIdx.x;
    if (i >= Etot) return;
    int d = (i < E) ? dst[i] : (i - E);   // self-loop edges appended: dst = node id
    atomicAdd(&counts[d], 1);
}

// single-block exclusive scan over n counts -> row_start[0..n]
__global__ __launch_bounds__(1024) void scan_kernel(const int* __restrict__ in,
                                                    int* __restrict__ out, int n) {
    __shared__ int wsum[16];
    __shared__ int s_carry;
    int tid = threadIdx.x;
    int lane = tid & 63, wid = tid >> 6;
    if (tid == 0) s_carry = 0;
    __syncthreads();
    for (int base = 0; base < n; base += 1024) {
        int i = base + tid;
        int v = (i < n) ? in[i] : 0;
        // wave inclusive scan
        int x = v;
        #pragma unroll
        for (int off = 1; off < 64; off <<= 1) {
            int y = __shfl_up(x, off, 64);
            if (lane >= off) x += y;
        }
        if (lane == 63) wsum[wid] = x;
        __syncthreads();
        if (wid == 0) {
            int w = (lane < 16) ? wsum[lane] : 0;
            #pragma unroll
            for (int off = 1; off < 16; off <<= 1) {
                int y = __shfl_up(w, off, 64);
                if (lane >= off) w += y;
            }
            if (lane < 16) wsum[lane] = w;  // inclusive wave sums
        }
        __syncthreads();
        int wave_off = (wid > 0) ? wsum[wid - 1] : 0;
        int incl = x + wave_off;
        int carry = s_carry;
        if (i < n) out[i] = carry + incl - v;  // exclusive
        __syncthreads();
        if (tid == 1023) s_carry = carry + wsum[15];
        __syncthreads();
    }
    if (tid == 0) out[n] = s_carry;
}

__global__ void fill_kernel(const int* __restrict__ src, const int* __restrict__ dst,
                            int E, int Etot, const int* __restrict__ row_start,
                            int* __restrict__ cursor, int* __restrict__ col_src) {
    int i = blockIdx.x * blockDim.x + threadIdx.x;
    if (i >= Etot) return;
    int d = (i < E) ? dst[i] : (i - E);
    int s = (i < E) ? src[i] : (i - E);
    int pos = atomicAdd(&cursor[d], 1);
    col_src[row_start[d] + pos] = s;
}

// ---------------- fp32 tiled GEMM: C[M,NC] = A[M,K] @ B[K,NC] ----------------
// NC in {128, 64}; K multiple of 16.

template <int NC>
__global__ __launch_bounds__(256) void gemm_kernel(const float* __restrict__ A,
                                                   const float* __restrict__ B,
                                                   float* __restrict__ C, int M, int K) {
    constexpr int BM = 64, BK = 16;
    constexpr int TN = NC / 32;  // 4 or 2
    __shared__ float As[BK][BM + 4];  // k-major, padded (row stride 272B, 16B-aligned)
    __shared__ float Bs[BK][NC];
    int tid = threadIdx.x;
    int tx = tid & 31;   // col group: 32 groups of TN
    int ty = tid >> 5;   // row group: 8 groups of 8
    int m0 = blockIdx.x * BM;
    float acc[8][TN];
    #pragma unroll
    for (int r = 0; r < 8; ++r)
        #pragma unroll
        for (int c = 0; c < TN; ++c) acc[r][c] = 0.f;

    for (int k0 = 0; k0 < K; k0 += BK) {
        // A tile: 64 rows x 16 k, one float4 per thread, store transposed
        {
            int row = tid >> 2, kq = tid & 3;
            int gr = m0 + row;
            float4 av = (gr < M)
                ? *reinterpret_cast<const float4*>(&A[(size_t)gr * K + k0 + kq * 4])
                : make_float4(0.f, 0.f, 0.f, 0.f);
            As[kq * 4 + 0][row] = av.x;
            As[kq * 4 + 1][row] = av.y;
            As[kq * 4 + 2][row] = av.z;
            As[kq * 4 + 3][row] = av.w;
        }
        // B tile: BK x NC
        {
            constexpr int per = (BK * NC) / (256 * 4);  // float4s per thread (2 or 1)
            #pragma unroll
            for (int pq = 0; pq < per; ++pq) {
                int idx = tid + pq * 256;
                int kr = idx / (NC / 4);
                int cc = (idx % (NC / 4)) * 4;
                float4 bv = *reinterpret_cast<const float4*>(&B[(size_t)(k0 + kr) * NC + cc]);
                *reinterpret_cast<float4*>(&Bs[kr][cc]) = bv;
            }
        }
        __syncthreads();
        #pragma unroll
        for (int k = 0; k < BK; ++k) {
            float a[8];
            float4 a0 = *reinterpret_cast<const float4*>(&As[k][ty * 8]);
            float4 a1 = *reinterpret_cast<const float4*>(&As[k][ty * 8 + 4]);
            a[0] = a0.x; a[1] = a0.y; a[2] = a0.z; a[3] = a0.w;
            a[4] = a1.x; a[5] = a1.y; a[6] = a1.z; a[7] = a1.w;
            float b[TN];
            if (TN == 4) {
                float4 bv = *reinterpret_cast<const float4*>(&Bs[k][tx * 4]);
                b[0] = bv.x; b[1] = bv.y; b[2] = bv.z; b[3] = bv.w;
            } else {
                float2 bv = *reinterpret_cast<const float2*>(&Bs[k][tx * 2]);
                b[0] = bv.x; b[1] = bv.y;
            }
            #pragma unroll
            for (int r = 0; r < 8; ++r)
                #pragma unroll
                for (int c = 0; c < TN; ++c) acc[r][c] += a[r] * b[c];
        }
        __syncthreads();
    }
    #pragma unroll
    for (int r = 0; r < 8; ++r) {
        int gr = m0 + ty * 8 + r;
        if (gr < M) {
            if (TN == 4) {
                float4 v = make_float4(acc[r][0], acc[r][1], acc[r][2], acc[r][3]);
                *reinterpret_cast<float4*>(&C[(size_t)gr * NC + tx * 4]) = v;
            } else {
                float2 v = make_float2(acc[r][0], acc[r][1]);
                *reinterpret_cast<float2*>(&C[(size_t)gr * NC + tx * 2]) = v;
            }
        }
    }
}

// ---------------- per-node score dots: s = h . a ----------------

template <int F>
__global__ __launch_bounds__(256) void score_kernel(const float* __restrict__ h,
                                                    const float* __restrict__ a_src,
                                                    const float* __restrict__ a_dst,
                                                    float* __restrict__ ss,
                                                    float* __restrict__ sd, int N) {
    int node = blockIdx.x * (blockDim.x >> 6) + (threadIdx.x >> 6);
    int lane = threadIdx.x & 63;
    if (node >= N) return;
    float vs = 0.f, vd = 0.f;
    #pragma unroll
    for (int t = 0; t < F / 64; ++t) {
        float hv = h[(size_t)node * F + t * 64 + lane];
        vs += hv * a_src[t * 64 + lane];
        vd += hv * a_dst[t * 64 + lane];
    }
    #pragma unroll
    for (int off = 32; off; off >>= 1) {
        vs += __shfl_xor(vs, off, 64);
        vd += __shfl_xor(vd, off, 64);
    }
    if (lane == 0) { ss[node] = vs; sd[node] = vd; }
}

// ---------------- per-dst-node softmax + weighted gather ----------------

template <int F, bool DO_ELU>
__global__ __launch_bounds__(256) void aggregate_kernel(
    const float* __restrict__ h, const float* __restrict__ ss,
    const float* __restrict__ sd, const int* __restrict__ row_start,
    const int* __restrict__ col_src, const float* __restrict__ bias,
    float* __restrict__ out, int N) {
    int node = blockIdx.x * (blockDim.x >> 6) + (threadIdx.x >> 6);
    int lane = threadIdx.x & 63;
    if (node >= N) return;
    int rs = row_start[node], re = row_start[node + 1];
    float sdn = sd[node];

    // phase 1: segment max (deg >= 1 from self-loop)
    float m = -INFINITY;
    for (int j = rs + lane; j < re; j += 64) {
        float e = leaky(ss[col_src[j]] + sdn);
        m = fmaxf(m, e);
    }
    #pragma unroll
    for (int off = 32; off; off >>= 1) m = fmaxf(m, __shfl_xor(m, off, 64));

    // phase 2: denom
    float den = 0.f;
    for (int j = rs + lane; j < re; j += 64) {
        float e = leaky(ss[col_src[j]] + sdn);
        den += __expf(e - m);
    }
    #pragma unroll
    for (int off = 32; off; off >>= 1) den += __shfl_xor(den, off, 64);
    float inv_den = 1.f / den;

    // phase 3: weighted accumulate over edges, coalesced h-row reads
    float acc[F / 64];
    #pragma unroll
    for (int t = 0; t < F / 64; ++t) acc[t] = 0.f;
    for (int j = rs; j < re; ++j) {
        int s = col_src[j];  // all lanes same address -> broadcast
        float e = leaky(ss[s] + sdn);
        float alpha = __expf(e - m) * inv_den;
        #pragma unroll
        for (int t = 0; t < F / 64; ++t)
            acc[t] += alpha * h[(size_t)s * F + t * 64 + lane];
    }
    #pragma unroll
    for (int t = 0; t < F / 64; ++t) {
        float v = acc[t] + bias[t * 64 + lane];
        if (DO_ELU) v = v > 0.f ? v : (__expf(v) - 1.f);
        out[(size_t)node * F + t * 64 + lane] = v;
    }
}

// ---------------- launch ----------------

extern "C" void kernel_launch(void* const* d_in, const int* in_sizes, int n_in,
                              void* d_out, int out_size, void* d_ws, size_t ws_size,
                              hipStream_t stream) {
    const float* x   = (const float*)d_in[0];
    const int*   ei  = (const int*)d_in[1];
    const float* W1  = (const float*)d_in[2];
    const float* a1s = (const float*)d_in[3];
    const float* a1d = (const float*)d_in[4];
    const float* b1  = (const float*)d_in[5];
    const float* W2  = (const float*)d_in[6];
    const float* a2s = (const float*)d_in[7];
    const float* a2d = (const float*)d_in[8];
    const float* b2  = (const float*)d_in[9];
    float* out = (float*)d_out;

    const int N    = in_sizes[0] / 256;  // IN_DIM = 256
    const int E    = in_sizes[1] / 2;
    const int Etot = E + N;
    const int* src = ei;
    const int* dst = ei + E;

    char* p = (char*)d_ws;
    auto carve = [&](size_t bytes) {
        char* r = p;
        p += (bytes + 255) & ~(size_t)255;
        return r;
    };
    float* h1  = (float*)carve((size_t)N * 128 * 4);
    float* x2  = (float*)carve((size_t)N * 128 * 4);
    float* h2  = (float*)carve((size_t)N * 64 * 4);
    float* s1s = (float*)carve((size_t)N * 4);
    float* s1d = (float*)carve((size_t)N * 4);
    float* s2s = (float*)carve((size_t)N * 4);
    float* s2d = (float*)carve((size_t)N * 4);
    int* counts = (int*)carve((size_t)N * 2 * 4);  // counts + cursor contiguous
    int* cursor = counts + N;
    int* row_start = (int*)carve((size_t)(N + 1) * 4);
    int* col_src   = (int*)carve((size_t)Etot * 4);

    hipMemsetAsync(counts, 0, (size_t)N * 2 * 4, stream);

    const int TB = 256;
    hist_kernel<<<(Etot + TB - 1) / TB, TB, 0, stream>>>(dst, E, Etot, counts);
    scan_kernel<<<1, 1024, 0, stream>>>(counts, row_start, N);
    fill_kernel<<<(Etot + TB - 1) / TB, TB, 0, stream>>>(src, dst, E, Etot,
                                                         row_start, cursor, col_src);

    // layer 1
    gemm_kernel<128><<<(N + 63) / 64, 256, 0, stream>>>(x, W1, h1, N, 256);
    score_kernel<128><<<(N + 3) / 4, 256, 0, stream>>>(h1, a1s, a1d, s1s, s1d, N);
    aggregate_kernel<128, true><<<(N + 3) / 4, 256, 0, stream>>>(
        h1, s1s, s1d, row_start, col_src, b1, x2, N);

    // layer 2
    gemm_kernel<64><<<(N + 63) / 64, 256, 0, stream>>>(x2, W2, h2, N, 128);
    score_kernel<64><<<(N + 3) / 4, 256, 0, stream>>>(h2, a2s, a2d, s2s, s2d, N);
    aggregate_kernel<64, false><<<(N + 3) / 4, 256, 0, stream>>>(
        h2, s2s, s2d, row_start, col_src, b2, out, N);
}

// Round 2
// 587.133 us; speedup vs baseline: 1.5365x; 1.5365x over previous
//
#include <hip/hip_runtime.h>
#include <hip/hip_bf16.h>
#include <cstdint>
#include <cstddef>

#define NEG_SLOPE 0.2f

static __device__ __forceinline__ float leaky(float v) { return v > 0.f ? v : NEG_SLOPE * v; }
static __device__ __forceinline__ float bf_lo(unsigned r) { return __uint_as_float(r << 16); }
static __device__ __forceinline__ float bf_hi(unsigned r) { return __uint_as_float(r & 0xffff0000u); }

// ---------------- CSR construction ----------------

__global__ void hist_kernel(const int* __restrict__ dst, int E, int Etot,
                            int* __restrict__ counts) {
    int i = blockIdx.x * blockDim.x + threadIdx.x;
    if (i >= Etot) return;
    int d = (i < E) ? dst[i] : (i - E);   // self-loop edges appended: dst = node id
    atomicAdd(&counts[d], 1);
}

// parallel exclusive scan: 1024 elems/block, 256 threads, 4 consecutive/thread
__global__ __launch_bounds__(256) void scan_sum_kernel(const int* __restrict__ in, int n,
                                                       int* __restrict__ bsum) {
    int base = blockIdx.x * 1024;
    int tid = threadIdx.x;
    int v = 0;
    int i0 = base + tid * 4;
    if (i0 + 3 < n) {
        int4 t4 = *reinterpret_cast<const int4*>(&in[i0]);
        v = t4.x + t4.y + t4.z + t4.w;
    } else {
        for (int q = 0; q < 4; ++q) { int i = i0 + q; if (i < n) v += in[i]; }
    }
    #pragma unroll
    for (int off = 32; off; off >>= 1) v += __shfl_xor(v, off, 64);
    __shared__ int ws[4];
    if ((tid & 63) == 0) ws[tid >> 6] = v;
    __syncthreads();
    if (tid == 0) bsum[blockIdx.x] = ws[0] + ws[1] + ws[2] + ws[3];
}

__global__ __launch_bounds__(256) void scan_mid_kernel(int* __restrict__ bsum, int nb,
                                                       int* __restrict__ totp) {
    int tid = threadIdx.x, lane = tid & 63, wid = tid >> 6;
    int v[4], run = 0;
    #pragma unroll
    for (int q = 0; q < 4; ++q) { int i = tid * 4 + q; v[q] = (i < nb) ? bsum[i] : 0; run += v[q]; }
    int x = run;
    #pragma unroll
    for (int off = 1; off < 64; off <<= 1) { int y = __shfl_up(x, off, 64); if (lane >= off) x += y; }
    __shared__ int ws[4];
    if (lane == 63) ws[wid] = x;
    __syncthreads();
    int wo = 0;
    #pragma unroll
    for (int w = 0; w < 4; ++w) if (w < wid) wo += ws[w];
    int p = wo + x - run;  // exclusive prefix for this thread's chunk
    #pragma unroll
    for (int q = 0; q < 4; ++q) { int i = tid * 4 + q; if (i < nb) bsum[i] = p; p += v[q]; }
    if (tid == 255) *totp = wo + x;  // grand total
}

__global__ __launch_bounds__(256) void scan_out_kernel(const int* __restrict__ in, int n,
                                                       const int* __restrict__ bsum,
                                                       int* __restrict__ out) {
    int base = blockIdx.x * 1024;
    int tid = threadIdx.x, lane = tid & 63, wid = tid >> 6;
    int v[4], run = 0;
    int i0 = base + tid * 4;
    if (i0 + 3 < n) {
        int4 t4 = *reinterpret_cast<const int4*>(&in[i0]);
        v[0] = t4.x; v[1] = t4.y; v[2] = t4.z; v[3] = t4.w;
    } else {
        for (int q = 0; q < 4; ++q) { int i = i0 + q; v[q] = (i < n) ? in[i] : 0; }
    }
    run = v[0] + v[1] + v[2] + v[3];
    int x = run;
    #pragma unroll
    for (int off = 1; off < 64; off <<= 1) { int y = __shfl_up(x, off, 64); if (lane >= off) x += y; }
    __shared__ int ws[4];
    if (lane == 63) ws[wid] = x;
    __syncthreads();
    int wo = 0;
    #pragma unroll
    for (int w = 0; w < 4; ++w) if (w < wid) wo += ws[w];
    int p = bsum[blockIdx.x] + wo + x - run;
    #pragma unroll
    for (int q = 0; q < 4; ++q) { int i = i0 + q; if (i < n) out[i] = p; p += v[q]; }
}

__global__ void fill_kernel(const int* __restrict__ src, const int* __restrict__ dst,
                            int E, int Etot, const int* __restrict__ row_start,
                            int* __restrict__ cursor, int* __restrict__ col_src) {
    int i = blockIdx.x * blockDim.x + threadIdx.x;
    if (i >= Etot) return;
    int d = (i < E) ? dst[i] : (i - E);
    int s = (i < E) ? src[i] : (i - E);
    int pos = atomicAdd(&cursor[d], 1);
    col_src[row_start[d] + pos] = s;
}

// ---------------- fp32 tiled GEMM: C[M,NC] = A[M,K] @ B[K,NC], C in bf16 ----------------

template <int NC>
__global__ __launch_bounds__(256) void gemm_kernel(const float* __restrict__ A,
                                                   const float* __restrict__ B,
                                                   __hip_bfloat16* __restrict__ C,
                                                   int M, int K) {
    constexpr int BM = 64, BK = 16;
    constexpr int TN = NC / 32;  // 4 or 2
    __shared__ float As[BK][BM + 4];
    __shared__ float Bs[BK][NC];
    int tid = threadIdx.x;
    int tx = tid & 31;
    int ty = tid >> 5;
    int m0 = blockIdx.x * BM;
    float acc[8][TN];
    #pragma unroll
    for (int r = 0; r < 8; ++r)
        #pragma unroll
        for (int c = 0; c < TN; ++c) acc[r][c] = 0.f;

    for (int k0 = 0; k0 < K; k0 += BK) {
        {
            int row = tid >> 2, kq = tid & 3;
            int gr = m0 + row;
            float4 av = (gr < M)
                ? *reinterpret_cast<const float4*>(&A[(size_t)gr * K + k0 + kq * 4])
                : make_float4(0.f, 0.f, 0.f, 0.f);
            As[kq * 4 + 0][row] = av.x;
            As[kq * 4 + 1][row] = av.y;
            As[kq * 4 + 2][row] = av.z;
            As[kq * 4 + 3][row] = av.w;
        }
        {
            constexpr int per = (BK * NC) / (256 * 4);
            #pragma unroll
            for (int pq = 0; pq < per; ++pq) {
                int idx = tid + pq * 256;
                int kr = idx / (NC / 4);
                int cc = (idx % (NC / 4)) * 4;
                float4 bv = *reinterpret_cast<const float4*>(&B[(size_t)(k0 + kr) * NC + cc]);
                *reinterpret_cast<float4*>(&Bs[kr][cc]) = bv;
            }
        }
        __syncthreads();
        #pragma unroll
        for (int k = 0; k < BK; ++k) {
            float a[8];
            float4 a0 = *reinterpret_cast<const float4*>(&As[k][ty * 8]);
            float4 a1 = *reinterpret_cast<const float4*>(&As[k][ty * 8 + 4]);
            a[0] = a0.x; a[1] = a0.y; a[2] = a0.z; a[3] = a0.w;
            a[4] = a1.x; a[5] = a1.y; a[6] = a1.z; a[7] = a1.w;
            float b[TN];
            if (TN == 4) {
                float4 bv = *reinterpret_cast<const float4*>(&Bs[k][tx * 4]);
                b[0] = bv.x; b[1] = bv.y; b[2] = bv.z; b[3] = bv.w;
            } else {
                float2 bv = *reinterpret_cast<const float2*>(&Bs[k][tx * 2]);
                b[0] = bv.x; b[1] = bv.y;
            }
            #pragma unroll
            for (int r = 0; r < 8; ++r)
                #pragma unroll
                for (int c = 0; c < TN; ++c) acc[r][c] += a[r] * b[c];
        }
        __syncthreads();
    }
    #pragma unroll
    for (int r = 0; r < 8; ++r) {
        int gr = m0 + ty * 8 + r;
        if (gr < M) {
            __hip_bfloat16 tmp[TN];
            #pragma unroll
            for (int c = 0; c < TN; ++c) tmp[c] = __float2bfloat16(acc[r][c]);
            if (TN == 4)
                *reinterpret_cast<uint2*>(&C[(size_t)gr * NC + tx * 4]) =
                    *reinterpret_cast<uint2*>(tmp);
            else
                *reinterpret_cast<unsigned*>(&C[(size_t)gr * NC + tx * 2]) =
                    *reinterpret_cast<unsigned*>(tmp);
        }
    }
}

// ---------------- per-node score dots: s = h . a (h in bf16) ----------------

template <int F>
__global__ __launch_bounds__(256) void score_kernel(const __hip_bfloat16* __restrict__ h,
                                                    const float* __restrict__ a_src,
                                                    const float* __restrict__ a_dst,
                                                    float* __restrict__ ss,
                                                    float* __restrict__ sd, int N) {
    int node = blockIdx.x * (blockDim.x >> 6) + (threadIdx.x >> 6);
    int lane = threadIdx.x & 63;
    if (node >= N) return;
    float vs = 0.f, vd = 0.f;
    if (F == 128) {
        unsigned r = *reinterpret_cast<const unsigned*>(&h[(size_t)node * F + lane * 2]);
        float2 asv = *reinterpret_cast<const float2*>(&a_src[lane * 2]);
        float2 adv = *reinterpret_cast<const float2*>(&a_dst[lane * 2]);
        float h0 = bf_lo(r), h1 = bf_hi(r);
        vs = h0 * asv.x + h1 * asv.y;
        vd = h0 * adv.x + h1 * adv.y;
    } else {
        unsigned r = (unsigned)*reinterpret_cast<const unsigned short*>(&h[(size_t)node * F + lane]);
        float h0 = __uint_as_float(r << 16);
        vs = h0 * a_src[lane];
        vd = h0 * a_dst[lane];
    }
    #pragma unroll
    for (int off = 32; off; off >>= 1) {
        vs += __shfl_xor(vs, off, 64);
        vd += __shfl_xor(vd, off, 64);
    }
    if (lane == 0) { ss[node] = vs; sd[node] = vd; }
}

// ---------------- per-dst-node softmax + weighted gather (h in bf16) ----------------

template <int F, bool DO_ELU>
__global__ __launch_bounds__(256) void aggregate_kernel(
    const __hip_bfloat16* __restrict__ h, const float* __restrict__ ss,
    const float* __restrict__ sd, const int* __restrict__ row_start,
    const int* __restrict__ col_src, const float* __restrict__ bias,
    float* __restrict__ out, int N) {
    constexpr int EPL = F / 64;  // elements per lane: 2 or 1
    int node = blockIdx.x * (blockDim.x >> 6) + (threadIdx.x >> 6);
    int lane = threadIdx.x & 63;
    if (node >= N) return;
    int rs = row_start[node], re = row_start[node + 1];
    int deg = re - rs;
    float sdn = sd[node];
    float acc[EPL];
    #pragma unroll
    for (int q = 0; q < EPL; ++q) acc[q] = 0.f;

    const unsigned* h32 = reinterpret_cast<const unsigned*>(h);
    const unsigned short* h16 = reinterpret_cast<const unsigned short*>(h);

    if (deg <= 64) {
        // one-pass: lane j holds edge rs+j
        int s_l = 0;
        float e_l = -INFINITY;
        if (lane < deg) {
            s_l = col_src[rs + lane];
            e_l = leaky(ss[s_l] + sdn);
        }
        float m = e_l;
        #pragma unroll
        for (int off = 32; off; off >>= 1) m = fmaxf(m, __shfl_xor(m, off, 64));
        float w_l = (lane < deg) ? __expf(e_l - m) : 0.f;
        float den = w_l;
        #pragma unroll
        for (int off = 32; off; off >>= 1) den += __shfl_xor(den, off, 64);
        float alpha_l = w_l / den;

        int j = 0;
        for (; j + 4 <= deg; j += 4) {
            int s0 = __shfl(s_l, j, 64), s1 = __shfl(s_l, j + 1, 64);
            int s2 = __shfl(s_l, j + 2, 64), s3 = __shfl(s_l, j + 3, 64);
            float a0 = __shfl(alpha_l, j, 64), a1 = __shfl(alpha_l, j + 1, 64);
            float a2 = __shfl(alpha_l, j + 2, 64), a3 = __shfl(alpha_l, j + 3, 64);
            if (EPL == 2) {
                unsigned r0 = h32[(size_t)s0 * (F / 2) + lane];
                unsigned r1 = h32[(size_t)s1 * (F / 2) + lane];
                unsigned r2 = h32[(size_t)s2 * (F / 2) + lane];
                unsigned r3 = h32[(size_t)s3 * (F / 2) + lane];
                acc[0] += a0 * bf_lo(r0); acc[1] += a0 * bf_hi(r0);
                acc[0] += a1 * bf_lo(r1); acc[1] += a1 * bf_hi(r1);
                acc[0] += a2 * bf_lo(r2); acc[1] += a2 * bf_hi(r2);
                acc[0] += a3 * bf_lo(r3); acc[1] += a3 * bf_hi(r3);
            } else {
                unsigned r0 = h16[(size_t)s0 * F + lane];
                unsigned r1 = h16[(size_t)s1 * F + lane];
                unsigned r2 = h16[(size_t)s2 * F + lane];
                unsigned r3 = h16[(size_t)s3 * F + lane];
                acc[0] += a0 * __uint_as_float(r0 << 16);
                acc[0] += a1 * __uint_as_float(r1 << 16);
                acc[0] += a2 * __uint_as_float(r2 << 16);
                acc[0] += a3 * __uint_as_float(r3 << 16);
            }
        }
        for (; j < deg; ++j) {
            int s0 = __shfl(s_l, j, 64);
            float a0 = __shfl(alpha_l, j, 64);
            if (EPL == 2) {
                unsigned r0 = h32[(size_t)s0 * (F / 2) + lane];
                acc[0] += a0 * bf_lo(r0); acc[1] += a0 * bf_hi(r0);
            } else {
                unsigned r0 = h16[(size_t)s0 * F + lane];
                acc[0] += a0 * __uint_as_float(r0 << 16);
            }
        }
    } else {
        // fallback: 3-pass (rare: deg > 64)
        float m = -INFINITY;
        for (int j = rs + lane; j < re; j += 64) {
            float e = leaky(ss[col_src[j]] + sdn);
            m = fmaxf(m, e);
        }
        #pragma unroll
        for (int off = 32; off; off >>= 1) m = fmaxf(m, __shfl_xor(m, off, 64));
        float den = 0.f;
        for (int j = rs + lane; j < re; j += 64) {
            float e = leaky(ss[col_src[j]] + sdn);
            den += __expf(e - m);
        }
        #pragma unroll
        for (int off = 32; off; off >>= 1) den += __shfl_xor(den, off, 64);
        float inv_den = 1.f / den;
        for (int j = rs; j < re; ++j) {
            int s = col_src[j];
            float e = leaky(ss[s] + sdn);
            float alpha = __expf(e - m) * inv_den;
            if (EPL == 2) {
                unsigned r0 = h32[(size_t)s * (F / 2) + lane];
                acc[0] += alpha * bf_lo(r0); acc[1] += alpha * bf_hi(r0);
            } else {
                unsigned r0 = h16[(size_t)s * F + lane];
                acc[0] += alpha * __uint_as_float(r0 << 16);
            }
        }
    }

    if (EPL == 2) {
        float2 bv = *reinterpret_cast<const float2*>(&bias[lane * 2]);
        float v0 = acc[0] + bv.x, v1 = acc[1] + bv.y;
        if (DO_ELU) {
            v0 = v0 > 0.f ? v0 : (__expf(v0) - 1.f);
            v1 = v1 > 0.f ? v1 : (__expf(v1) - 1.f);
        }
        *reinterpret_cast<float2*>(&out[(size_t)node * F + lane * 2]) = make_float2(v0, v1);
    } else {
        float v0 = acc[0] + bias[lane];
        if (DO_ELU) v0 = v0 > 0.f ? v0 : (__expf(v0) - 1.f);
        out[(size_t)node * F + lane] = v0;
    }
}

// ---------------- launch ----------------

extern "C" void kernel_launch(void* const* d_in, const int* in_sizes, int n_in,
                              void* d_out, int out_size, void* d_ws, size_t ws_size,
                              hipStream_t stream) {
    const float* x   = (const float*)d_in[0];
    const int*   ei  = (const int*)d_in[1];
    const float* W1  = (const float*)d_in[2];
    const float* a1s = (const float*)d_in[3];
    const float* a1d = (const float*)d_in[4];
    const float* b1  = (const float*)d_in[5];
    const float* W2  = (const float*)d_in[6];
    const float* a2s = (const float*)d_in[7];
    const float* a2d = (const float*)d_in[8];
    const float* b2  = (const float*)d_in[9];
    float* out = (float*)d_out;

    const int N    = in_sizes[0] / 256;  // IN_DIM = 256
    const int E    = in_sizes[1] / 2;
    const int Etot = E + N;
    const int* src = ei;
    const int* dst = ei + E;

    char* p = (char*)d_ws;
    auto carve = [&](size_t bytes) {
        char* r = p;
        p += (bytes + 255) & ~(size_t)255;
        return r;
    };
    __hip_bfloat16* h1 = (__hip_bfloat16*)carve((size_t)N * 128 * 2);
    __hip_bfloat16* h2 = (__hip_bfloat16*)carve((size_t)N * 64 * 2);
    float* x2  = (float*)carve((size_t)N * 128 * 4);
    float* s1s = (float*)carve((size_t)N * 4);
    float* s1d = (float*)carve((size_t)N * 4);
    float* s2s = (float*)carve((size_t)N * 4);
    float* s2d = (float*)carve((size_t)N * 4);
    int* counts = (int*)carve((size_t)N * 2 * 4);  // counts + cursor contiguous
    int* cursor = counts + N;
    int* row_start = (int*)carve((size_t)(N + 1) * 4);
    int* col_src   = (int*)carve((size_t)Etot * 4);
    int* bsum      = (int*)carve((size_t)2048 * 4);

    hipMemsetAsync(counts, 0, (size_t)N * 2 * 4, stream);

    const int TB = 256;
    const int nb = (N + 1023) / 1024;
    hist_kernel<<<(Etot + TB - 1) / TB, TB, 0, stream>>>(dst, E, Etot, counts);
    scan_sum_kernel<<<nb, 256, 0, stream>>>(counts, N, bsum);
    scan_mid_kernel<<<1, 256, 0, stream>>>(bsum, nb, row_start + N);
    scan_out_kernel<<<nb, 256, 0, stream>>>(counts, N, bsum, row_start);
    fill_kernel<<<(Etot + TB - 1) / TB, TB, 0, stream>>>(src, dst, E, Etot,
                                                         row_start, cursor, col_src);

    // layer 1
    gemm_kernel<128><<<(N + 63) / 64, 256, 0, stream>>>(x, W1, h1, N, 256);
    score_kernel<128><<<(N + 3) / 4, 256, 0, stream>>>(h1, a1s, a1d, s1s, s1d, N);
    aggregate_kernel<128, true><<<(N + 3) / 4, 256, 0, stream>>>(
        h1, s1s, s1d, row_start, col_src, b1, x2, N);

    // layer 2
    gemm_kernel<64><<<(N + 63) / 64, 256, 0, stream>>>(x2, W2, h2, N, 128);
    score_kernel<64><<<(N + 3) / 4, 256, 0, stream>>>(h2, a2s, a2d, s2s, s2d, N);
    aggregate_kernel<64, false><<<(N + 3) / 4, 256, 0, stream>>>(
        h2, s2s, s2d, row_start, col_src, b2, out, N);
}

// Round 3
// 557.024 us; speedup vs baseline: 1.6196x; 1.0541x over previous
//
#include <hip/hip_runtime.h>
#include <hip/hip_bf16.h>
#include <cstdint>
#include <cstddef>

#define NEG_SLOPE 0.2f

typedef __attribute__((ext_vector_type(8))) short short8;   // 8 bf16 (4 VGPRs)
typedef __attribute__((ext_vector_type(4))) float f32x4;

static __device__ __forceinline__ float leaky(float v) { return v > 0.f ? v : NEG_SLOPE * v; }
static __device__ __forceinline__ float bf_lo(unsigned r) { return __uint_as_float(r << 16); }
static __device__ __forceinline__ float bf_hi(unsigned r) { return __uint_as_float(r & 0xffff0000u); }
static __device__ __forceinline__ unsigned short f2bfbits(float f) {
    __hip_bfloat16 b = __float2bfloat16(f);
    return *reinterpret_cast<unsigned short*>(&b);
}

// ---------------- CSR construction ----------------

__global__ void hist_kernel(const int* __restrict__ dst, int E, int Etot,
                            int* __restrict__ counts) {
    int i = blockIdx.x * blockDim.x + threadIdx.x;
    if (i >= Etot) return;
    int d = (i < E) ? dst[i] : (i - E);   // self-loop edges appended: dst = node id
    atomicAdd(&counts[d], 1);
}

__global__ __launch_bounds__(256) void scan_sum_kernel(const int* __restrict__ in, int n,
                                                       int* __restrict__ bsum) {
    int base = blockIdx.x * 1024;
    int tid = threadIdx.x;
    int v = 0;
    int i0 = base + tid * 4;
    if (i0 + 3 < n) {
        int4 t4 = *reinterpret_cast<const int4*>(&in[i0]);
        v = t4.x + t4.y + t4.z + t4.w;
    } else {
        for (int q = 0; q < 4; ++q) { int i = i0 + q; if (i < n) v += in[i]; }
    }
    #pragma unroll
    for (int off = 32; off; off >>= 1) v += __shfl_xor(v, off, 64);
    __shared__ int ws[4];
    if ((tid & 63) == 0) ws[tid >> 6] = v;
    __syncthreads();
    if (tid == 0) bsum[blockIdx.x] = ws[0] + ws[1] + ws[2] + ws[3];
}

__global__ __launch_bounds__(256) void scan_mid_kernel(int* __restrict__ bsum, int nb,
                                                       int* __restrict__ totp) {
    int tid = threadIdx.x, lane = tid & 63, wid = tid >> 6;
    int v[4], run = 0;
    #pragma unroll
    for (int q = 0; q < 4; ++q) { int i = tid * 4 + q; v[q] = (i < nb) ? bsum[i] : 0; run += v[q]; }
    int x = run;
    #pragma unroll
    for (int off = 1; off < 64; off <<= 1) { int y = __shfl_up(x, off, 64); if (lane >= off) x += y; }
    __shared__ int ws[4];
    if (lane == 63) ws[wid] = x;
    __syncthreads();
    int wo = 0;
    #pragma unroll
    for (int w = 0; w < 4; ++w) if (w < wid) wo += ws[w];
    int p = wo + x - run;
    #pragma unroll
    for (int q = 0; q < 4; ++q) { int i = tid * 4 + q; if (i < nb) bsum[i] = p; p += v[q]; }
    if (tid == 255) *totp = wo + x;
}

__global__ __launch_bounds__(256) void scan_out_kernel(const int* __restrict__ in, int n,
                                                       const int* __restrict__ bsum,
                                                       int* __restrict__ out) {
    int base = blockIdx.x * 1024;
    int tid = threadIdx.x, lane = tid & 63, wid = tid >> 6;
    int v[4];
    int i0 = base + tid * 4;
    if (i0 + 3 < n) {
        int4 t4 = *reinterpret_cast<const int4*>(&in[i0]);
        v[0] = t4.x; v[1] = t4.y; v[2] = t4.z; v[3] = t4.w;
    } else {
        for (int q = 0; q < 4; ++q) { int i = i0 + q; v[q] = (i < n) ? in[i] : 0; }
    }
    int run = v[0] + v[1] + v[2] + v[3];
    int x = run;
    #pragma unroll
    for (int off = 1; off < 64; off <<= 1) { int y = __shfl_up(x, off, 64); if (lane >= off) x += y; }
    __shared__ int ws[4];
    if (lane == 63) ws[wid] = x;
    __syncthreads();
    int wo = 0;
    #pragma unroll
    for (int w = 0; w < 4; ++w) if (w < wid) wo += ws[w];
    int p = bsum[blockIdx.x] + wo + x - run;
    #pragma unroll
    for (int q = 0; q < 4; ++q) { int i = i0 + q; if (i < n) out[i] = p; p += v[q]; }
}

__global__ void fill_kernel(const int* __restrict__ src, const int* __restrict__ dst,
                            int E, int Etot, const int* __restrict__ row_start,
                            int* __restrict__ cursor, int* __restrict__ col_src) {
    int i = blockIdx.x * blockDim.x + threadIdx.x;
    if (i >= Etot) return;
    int d = (i < E) ? dst[i] : (i - E);
    int s = (i < E) ? src[i] : (i - E);
    int pos = atomicAdd(&cursor[d], 1);
    col_src[row_start[d] + pos] = s;
}

// ---------------- W transpose + bf16 convert: Wt[c][k] = bf16(W[k][c]) ----------------

__global__ void wt_kernel(const float* __restrict__ W, unsigned short* __restrict__ Wt,
                          int K, int C) {
    int i = blockIdx.x * blockDim.x + threadIdx.x;
    if (i >= K * C) return;
    int c = i / K, k = i % K;
    Wt[i] = f2bfbits(W[(size_t)k * C + c]);
}

// ---------------- MFMA GEMM1: h1[M,128] = bf16( x[M,256] @ W1 ) ----------------
// A fp32 (converted in-register), B = Wt bf16 col-major [NC][K], C bf16.

__global__ __launch_bounds__(256) void mfma_gemm1(const float* __restrict__ A,
                                                  const unsigned short* __restrict__ Wt,
                                                  unsigned short* __restrict__ C, int M) {
    constexpr int K = 256, NC = 128;
    int wave = threadIdx.x >> 6, lane = threadIdx.x & 63;
    int lrow = lane & 15, kg = lane >> 4;
    int m_base = blockIdx.x * 64;
    int n0 = wave * 32;

    const float* ap[4];
    #pragma unroll
    for (int mi = 0; mi < 4; ++mi) {
        int row = m_base + mi * 16 + lrow;
        if (row >= M) row = M - 1;
        ap[mi] = A + (size_t)row * K + kg * 8;
    }
    const short8* bp0 = reinterpret_cast<const short8*>(Wt + (size_t)(n0 + lrow) * K + kg * 8);
    const short8* bp1 = reinterpret_cast<const short8*>(Wt + (size_t)(n0 + 16 + lrow) * K + kg * 8);

    f32x4 acc[4][2];
    #pragma unroll
    for (int mi = 0; mi < 4; ++mi)
        #pragma unroll
        for (int ni = 0; ni < 2; ++ni) acc[mi][ni] = {0.f, 0.f, 0.f, 0.f};

    #pragma unroll 2
    for (int k0 = 0; k0 < K; k0 += 32) {
        short8 afr[4];
        #pragma unroll
        for (int mi = 0; mi < 4; ++mi) {
            float4 q0 = *reinterpret_cast<const float4*>(ap[mi] + k0);
            float4 q1 = *reinterpret_cast<const float4*>(ap[mi] + k0 + 4);
            short8 a;
            a[0] = (short)f2bfbits(q0.x); a[1] = (short)f2bfbits(q0.y);
            a[2] = (short)f2bfbits(q0.z); a[3] = (short)f2bfbits(q0.w);
            a[4] = (short)f2bfbits(q1.x); a[5] = (short)f2bfbits(q1.y);
            a[6] = (short)f2bfbits(q1.z); a[7] = (short)f2bfbits(q1.w);
            afr[mi] = a;
        }
        short8 bfr[2];
        bfr[0] = bp0[k0 >> 3];   // (k0 + kg*8 elements already in base) -> offset k0/8 short8s
        bfr[1] = bp1[k0 >> 3];
        #pragma unroll
        for (int mi = 0; mi < 4; ++mi)
            #pragma unroll
            for (int ni = 0; ni < 2; ++ni)
                acc[mi][ni] = __builtin_amdgcn_mfma_f32_16x16x32_bf16(afr[mi], bfr[ni],
                                                                      acc[mi][ni], 0, 0, 0);
    }

    #pragma unroll
    for (int mi = 0; mi < 4; ++mi) {
        int row_b = m_base + mi * 16 + kg * 4;
        #pragma unroll
        for (int r = 0; r < 4; ++r) {
            int row = row_b + r;
            if (row < M) {
                #pragma unroll
                for (int ni = 0; ni < 2; ++ni)
                    C[(size_t)row * NC + n0 + ni * 16 + lrow] = (unsigned short)f2bfbits(acc[mi][ni][r]);
            }
        }
    }
}

// ---------------- MFMA GEMM2: h2[M,64] = bf16( x2[M,128] @ W2 ), A bf16 ----------------

__global__ __launch_bounds__(256) void mfma_gemm2(const unsigned short* __restrict__ A,
                                                  const unsigned short* __restrict__ Wt,
                                                  unsigned short* __restrict__ C, int M) {
    constexpr int K = 128, NC = 64;
    int wave = threadIdx.x >> 6, lane = threadIdx.x & 63;
    int lrow = lane & 15, kg = lane >> 4;
    int m_base = blockIdx.x * 64;
    int n0 = wave * 16;

    const short8* ap[4];
    #pragma unroll
    for (int mi = 0; mi < 4; ++mi) {
        int row = m_base + mi * 16 + lrow;
        if (row >= M) row = M - 1;
        ap[mi] = reinterpret_cast<const short8*>(A + (size_t)row * K + kg * 8);
    }
    const short8* bp = reinterpret_cast<const short8*>(Wt + (size_t)(n0 + lrow) * K + kg * 8);

    f32x4 acc[4];
    #pragma unroll
    for (int mi = 0; mi < 4; ++mi) acc[mi] = {0.f, 0.f, 0.f, 0.f};

    #pragma unroll
    for (int k0 = 0; k0 < K; k0 += 32) {
        short8 bfr = bp[k0 >> 3];
        #pragma unroll
        for (int mi = 0; mi < 4; ++mi) {
            short8 afr = ap[mi][k0 >> 3];
            acc[mi] = __builtin_amdgcn_mfma_f32_16x16x32_bf16(afr, bfr, acc[mi], 0, 0, 0);
        }
    }

    #pragma unroll
    for (int mi = 0; mi < 4; ++mi) {
        int row_b = m_base + mi * 16 + kg * 4;
        #pragma unroll
        for (int r = 0; r < 4; ++r) {
            int row = row_b + r;
            if (row < M)
                C[(size_t)row * NC + n0 + lrow] = (unsigned short)f2bfbits(acc[mi][r]);
        }
    }
}

// ---------------- per-node score dots: s = h . a (h in bf16) ----------------

template <int F>
__global__ __launch_bounds__(256) void score_kernel(const __hip_bfloat16* __restrict__ h,
                                                    const float* __restrict__ a_src,
                                                    const float* __restrict__ a_dst,
                                                    float* __restrict__ ss,
                                                    float* __restrict__ sd, int N) {
    int node = blockIdx.x * (blockDim.x >> 6) + (threadIdx.x >> 6);
    int lane = threadIdx.x & 63;
    if (node >= N) return;
    float vs = 0.f, vd = 0.f;
    if (F == 128) {
        unsigned r = *reinterpret_cast<const unsigned*>(&h[(size_t)node * F + lane * 2]);
        float2 asv = *reinterpret_cast<const float2*>(&a_src[lane * 2]);
        float2 adv = *reinterpret_cast<const float2*>(&a_dst[lane * 2]);
        float h0 = bf_lo(r), h1 = bf_hi(r);
        vs = h0 * asv.x + h1 * asv.y;
        vd = h0 * adv.x + h1 * adv.y;
    } else {
        unsigned r = (unsigned)*reinterpret_cast<const unsigned short*>(&h[(size_t)node * F + lane]);
        float h0 = __uint_as_float(r << 16);
        vs = h0 * a_src[lane];
        vd = h0 * a_dst[lane];
    }
    #pragma unroll
    for (int off = 32; off; off >>= 1) {
        vs += __shfl_xor(vs, off, 64);
        vd += __shfl_xor(vd, off, 64);
    }
    if (lane == 0) { ss[node] = vs; sd[node] = vd; }
}

// ---------------- per-dst-node softmax + weighted gather (h in bf16) ----------------

template <int F, bool DO_ELU, bool OUT_BF16>
__global__ __launch_bounds__(256) void aggregate_kernel(
    const __hip_bfloat16* __restrict__ h, const float* __restrict__ ss,
    const float* __restrict__ sd, const int* __restrict__ row_start,
    const int* __restrict__ col_src, const float* __restrict__ bias,
    void* __restrict__ out_raw, int N) {
    constexpr int EPL = F / 64;  // elements per lane: 2 or 1
    int node = blockIdx.x * (blockDim.x >> 6) + (threadIdx.x >> 6);
    int lane = threadIdx.x & 63;
    if (node >= N) return;
    int rs = row_start[node], re = row_start[node + 1];
    int deg = re - rs;
    float sdn = sd[node];
    float acc[EPL];
    #pragma unroll
    for (int q = 0; q < EPL; ++q) acc[q] = 0.f;

    const unsigned* h32 = reinterpret_cast<const unsigned*>(h);
    const unsigned short* h16 = reinterpret_cast<const unsigned short*>(h);

    if (deg <= 64) {
        int s_l = 0;
        float e_l = -INFINITY;
        if (lane < deg) {
            s_l = col_src[rs + lane];
            e_l = leaky(ss[s_l] + sdn);
        }
        float m = e_l;
        #pragma unroll
        for (int off = 32; off; off >>= 1) m = fmaxf(m, __shfl_xor(m, off, 64));
        float w_l = (lane < deg) ? __expf(e_l - m) : 0.f;
        float den = w_l;
        #pragma unroll
        for (int off = 32; off; off >>= 1) den += __shfl_xor(den, off, 64);
        float alpha_l = w_l / den;

        int j = 0;
        for (; j + 4 <= deg; j += 4) {
            int s0 = __shfl(s_l, j, 64), s1 = __shfl(s_l, j + 1, 64);
            int s2 = __shfl(s_l, j + 2, 64), s3 = __shfl(s_l, j + 3, 64);
            float a0 = __shfl(alpha_l, j, 64), a1 = __shfl(alpha_l, j + 1, 64);
            float a2 = __shfl(alpha_l, j + 2, 64), a3 = __shfl(alpha_l, j + 3, 64);
            if (EPL == 2) {
                unsigned r0 = h32[(size_t)s0 * (F / 2) + lane];
                unsigned r1 = h32[(size_t)s1 * (F / 2) + lane];
                unsigned r2 = h32[(size_t)s2 * (F / 2) + lane];
                unsigned r3 = h32[(size_t)s3 * (F / 2) + lane];
                acc[0] += a0 * bf_lo(r0); acc[1] += a0 * bf_hi(r0);
                acc[0] += a1 * bf_lo(r1); acc[1] += a1 * bf_hi(r1);
                acc[0] += a2 * bf_lo(r2); acc[1] += a2 * bf_hi(r2);
                acc[0] += a3 * bf_lo(r3); acc[1] += a3 * bf_hi(r3);
            } else {
                unsigned r0 = h16[(size_t)s0 * F + lane];
                unsigned r1 = h16[(size_t)s1 * F + lane];
                unsigned r2 = h16[(size_t)s2 * F + lane];
                unsigned r3 = h16[(size_t)s3 * F + lane];
                acc[0] += a0 * __uint_as_float(r0 << 16);
                acc[0] += a1 * __uint_as_float(r1 << 16);
                acc[0] += a2 * __uint_as_float(r2 << 16);
                acc[0] += a3 * __uint_as_float(r3 << 16);
            }
        }
        for (; j < deg; ++j) {
            int s0 = __shfl(s_l, j, 64);
            float a0 = __shfl(alpha_l, j, 64);
            if (EPL == 2) {
                unsigned r0 = h32[(size_t)s0 * (F / 2) + lane];
                acc[0] += a0 * bf_lo(r0); acc[1] += a0 * bf_hi(r0);
            } else {
                unsigned r0 = h16[(size_t)s0 * F + lane];
                acc[0] += a0 * __uint_as_float(r0 << 16);
            }
        }
    } else {
        float m = -INFINITY;
        for (int j = rs + lane; j < re; j += 64) {
            float e = leaky(ss[col_src[j]] + sdn);
            m = fmaxf(m, e);
        }
        #pragma unroll
        for (int off = 32; off; off >>= 1) m = fmaxf(m, __shfl_xor(m, off, 64));
        float den = 0.f;
        for (int j = rs + lane; j < re; j += 64) {
            float e = leaky(ss[col_src[j]] + sdn);
            den += __expf(e - m);
        }
        #pragma unroll
        for (int off = 32; off; off >>= 1) den += __shfl_xor(den, off, 64);
        float inv_den = 1.f / den;
        for (int j = rs; j < re; ++j) {
            int s = col_src[j];
            float e = leaky(ss[s] + sdn);
            float alpha = __expf(e - m) * inv_den;
            if (EPL == 2) {
                unsigned r0 = h32[(size_t)s * (F / 2) + lane];
                acc[0] += alpha * bf_lo(r0); acc[1] += alpha * bf_hi(r0);
            } else {
                unsigned r0 = h16[(size_t)s * F + lane];
                acc[0] += alpha * __uint_as_float(r0 << 16);
            }
        }
    }

    if (EPL == 2) {
        float2 bv = *reinterpret_cast<const float2*>(&bias[lane * 2]);
        float v0 = acc[0] + bv.x, v1 = acc[1] + bv.y;
        if (DO_ELU) {
            v0 = v0 > 0.f ? v0 : (__expf(v0) - 1.f);
            v1 = v1 > 0.f ? v1 : (__expf(v1) - 1.f);
        }
        if (OUT_BF16) {
            unsigned pk = (unsigned)f2bfbits(v0) | ((unsigned)f2bfbits(v1) << 16);
            reinterpret_cast<unsigned*>(out_raw)[(size_t)node * (F / 2) + lane] = pk;
        } else {
            reinterpret_cast<float2*>(out_raw)[(size_t)node * (F / 2) + lane] =
                make_float2(v0, v1);
        }
    } else {
        float v0 = acc[0] + bias[lane];
        if (DO_ELU) v0 = v0 > 0.f ? v0 : (__expf(v0) - 1.f);
        reinterpret_cast<float*>(out_raw)[(size_t)node * F + lane] = v0;
    }
}

// ---------------- launch ----------------

extern "C" void kernel_launch(void* const* d_in, const int* in_sizes, int n_in,
                              void* d_out, int out_size, void* d_ws, size_t ws_size,
                              hipStream_t stream) {
    const float* x   = (const float*)d_in[0];
    const int*   ei  = (const int*)d_in[1];
    const float* W1  = (const float*)d_in[2];
    const float* a1s = (const float*)d_in[3];
    const float* a1d = (const float*)d_in[4];
    const float* b1  = (const float*)d_in[5];
    const float* W2  = (const float*)d_in[6];
    const float* a2s = (const float*)d_in[7];
    const float* a2d = (const float*)d_in[8];
    const float* b2  = (const float*)d_in[9];

    const int N    = in_sizes[0] / 256;  // IN_DIM = 256
    const int E    = in_sizes[1] / 2;
    const int Etot = E + N;
    const int* src = ei;
    const int* dst = ei + E;

    char* p = (char*)d_ws;
    auto carve = [&](size_t bytes) {
        char* r = p;
        p += (bytes + 255) & ~(size_t)255;
        return r;
    };
    unsigned short* h1  = (unsigned short*)carve((size_t)N * 128 * 2);
    unsigned short* h2  = (unsigned short*)carve((size_t)N * 64 * 2);
    unsigned short* x2b = (unsigned short*)carve((size_t)N * 128 * 2);
    unsigned short* wt1 = (unsigned short*)carve((size_t)128 * 256 * 2);
    unsigned short* wt2 = (unsigned short*)carve((size_t)64 * 128 * 2);
    float* s1s = (float*)carve((size_t)N * 4);
    float* s1d = (float*)carve((size_t)N * 4);
    float* s2s = (float*)carve((size_t)N * 4);
    float* s2d = (float*)carve((size_t)N * 4);
    int* counts = (int*)carve((size_t)N * 2 * 4);  // counts + cursor contiguous
    int* cursor = counts + N;
    int* row_start = (int*)carve((size_t)(N + 1) * 4);
    int* col_src   = (int*)carve((size_t)Etot * 4);
    int* bsum      = (int*)carve((size_t)2048 * 4);

    hipMemsetAsync(counts, 0, (size_t)N * 2 * 4, stream);

    const int TB = 256;
    const int nb = (N + 1023) / 1024;

    wt_kernel<<<(128 * 256 + TB - 1) / TB, TB, 0, stream>>>(W1, wt1, 256, 128);
    wt_kernel<<<(64 * 128 + TB - 1) / TB, TB, 0, stream>>>(W2, wt2, 128, 64);

    hist_kernel<<<(Etot + TB - 1) / TB, TB, 0, stream>>>(dst, E, Etot, counts);
    scan_sum_kernel<<<nb, 256, 0, stream>>>(counts, N, bsum);
    scan_mid_kernel<<<1, 256, 0, stream>>>(bsum, nb, row_start + N);
    scan_out_kernel<<<nb, 256, 0, stream>>>(counts, N, bsum, row_start);
    fill_kernel<<<(Etot + TB - 1) / TB, TB, 0, stream>>>(src, dst, E, Etot,
                                                         row_start, cursor, col_src);

    // layer 1
    mfma_gemm1<<<(N + 63) / 64, 256, 0, stream>>>(x, wt1, h1, N);
    score_kernel<128><<<(N + 3) / 4, 256, 0, stream>>>((const __hip_bfloat16*)h1,
                                                       a1s, a1d, s1s, s1d, N);
    aggregate_kernel<128, true, true><<<(N + 3) / 4, 256, 0, stream>>>(
        (const __hip_bfloat16*)h1, s1s, s1d, row_start, col_src, b1, x2b, N);

    // layer 2
    mfma_gemm2<<<(N + 63) / 64, 256, 0, stream>>>(x2b, wt2, h2, N);
    score_kernel<64><<<(N + 3) / 4, 256, 0, stream>>>((const __hip_bfloat16*)h2,
                                                      a2s, a2d, s2s, s2d, N);
    aggregate_kernel<64, false, false><<<(N + 3) / 4, 256, 0, stream>>>(
        (const __hip_bfloat16*)h2, s2s, s2d, row_start, col_src, b2, d_out, N);
}

// Round 5
// 516.043 us; speedup vs baseline: 1.7482x; 1.0794x over previous
//
#include <hip/hip_runtime.h>
#include <hip/hip_bf16.h>
#include <cstdint>
#include <cstddef>

#define NEG_SLOPE 0.2f

typedef __attribute__((ext_vector_type(8))) short short8;   // 8 bf16 (4 VGPRs)
typedef __attribute__((ext_vector_type(4))) float f32x4;

static __device__ __forceinline__ float leaky(float v) { return v > 0.f ? v : NEG_SLOPE * v; }
static __device__ __forceinline__ float bf_lo(unsigned r) { return __uint_as_float(r << 16); }
static __device__ __forceinline__ float bf_hi(unsigned r) { return __uint_as_float(r & 0xffff0000u); }
static __device__ __forceinline__ unsigned short f2bfbits(float f) {
    __hip_bfloat16 b = __float2bfloat16(f);
    return *reinterpret_cast<unsigned short*>(&b);
}

// ---------------- CSR construction ----------------
// hist + per-edge stable rank in ONE atomic pass: atomicAdd's return IS the rank.

__global__ void hist_rank_kernel(const int* __restrict__ dst, int E, int Etot,
                                 int* __restrict__ counts, int* __restrict__ rank) {
    int i = blockIdx.x * blockDim.x + threadIdx.x;
    if (i >= Etot) return;
    int d = (i < E) ? dst[i] : (i - E);   // self-loop edges appended: dst = node id
    rank[i] = atomicAdd(&counts[d], 1);
}

__global__ __launch_bounds__(256) void scan_sum_kernel(const int* __restrict__ in, int n,
                                                       int* __restrict__ bsum) {
    int base = blockIdx.x * 1024;
    int tid = threadIdx.x;
    int v = 0;
    int i0 = base + tid * 4;
    if (i0 + 3 < n) {
        int4 t4 = *reinterpret_cast<const int4*>(&in[i0]);
        v = t4.x + t4.y + t4.z + t4.w;
    } else {
        for (int q = 0; q < 4; ++q) { int i = i0 + q; if (i < n) v += in[i]; }
    }
    #pragma unroll
    for (int off = 32; off; off >>= 1) v += __shfl_xor(v, off, 64);
    __shared__ int ws[4];
    if ((tid & 63) == 0) ws[tid >> 6] = v;
    __syncthreads();
    if (tid == 0) bsum[blockIdx.x] = ws[0] + ws[1] + ws[2] + ws[3];
}

__global__ __launch_bounds__(256) void scan_mid_kernel(int* __restrict__ bsum, int nb,
                                                       int* __restrict__ totp) {
    int tid = threadIdx.x, lane = tid & 63, wid = tid >> 6;
    int v[4], run = 0;
    #pragma unroll
    for (int q = 0; q < 4; ++q) { int i = tid * 4 + q; v[q] = (i < nb) ? bsum[i] : 0; run += v[q]; }
    int x = run;
    #pragma unroll
    for (int off = 1; off < 64; off <<= 1) { int y = __shfl_up(x, off, 64); if (lane >= off) x += y; }
    __shared__ int ws[4];
    if (lane == 63) ws[wid] = x;
    __syncthreads();
    int wo = 0;
    #pragma unroll
    for (int w = 0; w < 4; ++w) if (w < wid) wo += ws[w];
    int p = wo + x - run;
    #pragma unroll
    for (int q = 0; q < 4; ++q) { int i = tid * 4 + q; if (i < nb) bsum[i] = p; p += v[q]; }
    if (tid == 255) *totp = wo + x;
}

__global__ __launch_bounds__(256) void scan_out_kernel(const int* __restrict__ in, int n,
                                                       const int* __restrict__ bsum,
                                                       int* __restrict__ out) {
    int base = blockIdx.x * 1024;
    int tid = threadIdx.x, lane = tid & 63, wid = tid >> 6;
    int v[4];
    int i0 = base + tid * 4;
    if (i0 + 3 < n) {
        int4 t4 = *reinterpret_cast<const int4*>(&in[i0]);
        v[0] = t4.x; v[1] = t4.y; v[2] = t4.z; v[3] = t4.w;
    } else {
        for (int q = 0; q < 4; ++q) { int i = i0 + q; v[q] = (i < n) ? in[i] : 0; }
    }
    int run = v[0] + v[1] + v[2] + v[3];
    int x = run;
    #pragma unroll
    for (int off = 1; off < 64; off <<= 1) { int y = __shfl_up(x, off, 64); if (lane >= off) x += y; }
    __shared__ int ws[4];
    if (lane == 63) ws[wid] = x;
    __syncthreads();
    int wo = 0;
    #pragma unroll
    for (int w = 0; w < 4; ++w) if (w < wid) wo += ws[w];
    int p = bsum[blockIdx.x] + wo + x - run;
    #pragma unroll
    for (int q = 0; q < 4; ++q) { int i = i0 + q; if (i < n) out[i] = p; p += v[q]; }
}

// atomic-free scatter using precomputed rank
__global__ void fill_kernel(const int* __restrict__ src, const int* __restrict__ dst,
                            int E, int Etot, const int* __restrict__ row_start,
                            const int* __restrict__ rank, int* __restrict__ col_src) {
    int i = blockIdx.x * blockDim.x + threadIdx.x;
    if (i >= Etot) return;
    int d = (i < E) ? dst[i] : (i - E);
    int s = (i < E) ? src[i] : (i - E);
    col_src[row_start[d] + rank[i]] = s;
}

// ---------------- W transpose + bf16 convert: Wt[c][k] = bf16(W[k][c]) ----------------

__global__ void wt_kernel(const float* __restrict__ W, unsigned short* __restrict__ Wt,
                          int K, int C) {
    int i = blockIdx.x * blockDim.x + threadIdx.x;
    if (i >= K * C) return;
    int c = i / K, k = i % K;
    Wt[i] = f2bfbits(W[(size_t)k * C + c]);
}

// ---------------- MFMA GEMM1: h1[M,128] = bf16( x[M,256] @ W1 ) ----------------

__global__ __launch_bounds__(256) void mfma_gemm1(const float* __restrict__ A,
                                                  const unsigned short* __restrict__ Wt,
                                                  unsigned short* __restrict__ C, int M) {
    constexpr int K = 256, NC = 128;
    int wave = threadIdx.x >> 6, lane = threadIdx.x & 63;
    int lrow = lane & 15, kg = lane >> 4;
    int m_base = blockIdx.x * 64;
    int n0 = wave * 32;

    const float* ap[4];
    #pragma unroll
    for (int mi = 0; mi < 4; ++mi) {
        int row = m_base + mi * 16 + lrow;
        if (row >= M) row = M - 1;
        ap[mi] = A + (size_t)row * K + kg * 8;
    }
    const short8* bp0 = reinterpret_cast<const short8*>(Wt + (size_t)(n0 + lrow) * K + kg * 8);
    const short8* bp1 = reinterpret_cast<const short8*>(Wt + (size_t)(n0 + 16 + lrow) * K + kg * 8);

    f32x4 acc[4][2];
    #pragma unroll
    for (int mi = 0; mi < 4; ++mi)
        #pragma unroll
        for (int ni = 0; ni < 2; ++ni) acc[mi][ni] = {0.f, 0.f, 0.f, 0.f};

    #pragma unroll 2
    for (int k0 = 0; k0 < K; k0 += 32) {
        short8 afr[4];
        #pragma unroll
        for (int mi = 0; mi < 4; ++mi) {
            float4 q0 = *reinterpret_cast<const float4*>(ap[mi] + k0);
            float4 q1 = *reinterpret_cast<const float4*>(ap[mi] + k0 + 4);
            short8 a;
            a[0] = (short)f2bfbits(q0.x); a[1] = (short)f2bfbits(q0.y);
            a[2] = (short)f2bfbits(q0.z); a[3] = (short)f2bfbits(q0.w);
            a[4] = (short)f2bfbits(q1.x); a[5] = (short)f2bfbits(q1.y);
            a[6] = (short)f2bfbits(q1.z); a[7] = (short)f2bfbits(q1.w);
            afr[mi] = a;
        }
        short8 bfr[2];
        bfr[0] = bp0[k0 >> 3];
        bfr[1] = bp1[k0 >> 3];
        #pragma unroll
        for (int mi = 0; mi < 4; ++mi)
            #pragma unroll
            for (int ni = 0; ni < 2; ++ni)
                acc[mi][ni] = __builtin_amdgcn_mfma_f32_16x16x32_bf16(afr[mi], bfr[ni],
                                                                      acc[mi][ni], 0, 0, 0);
    }

    #pragma unroll
    for (int mi = 0; mi < 4; ++mi) {
        int row_b = m_base + mi * 16 + kg * 4;
        #pragma unroll
        for (int r = 0; r < 4; ++r) {
            int row = row_b + r;
            if (row < M) {
                #pragma unroll
                for (int ni = 0; ni < 2; ++ni)
                    C[(size_t)row * NC + n0 + ni * 16 + lrow] = (unsigned short)f2bfbits(acc[mi][ni][r]);
            }
        }
    }
}

// ---------------- MFMA GEMM2: h2[M,64] = bf16( x2[M,128] @ W2 ), A bf16 ----------------

__global__ __launch_bounds__(256) void mfma_gemm2(const unsigned short* __restrict__ A,
                                                  const unsigned short* __restrict__ Wt,
                                                  unsigned short* __restrict__ C, int M) {
    constexpr int K = 128, NC = 64;
    int wave = threadIdx.x >> 6, lane = threadIdx.x & 63;
    int lrow = lane & 15, kg = lane >> 4;
    int m_base = blockIdx.x * 64;
    int n0 = wave * 16;

    const short8* ap[4];
    #pragma unroll
    for (int mi = 0; mi < 4; ++mi) {
        int row = m_base + mi * 16 + lrow;
        if (row >= M) row = M - 1;
        ap[mi] = reinterpret_cast<const short8*>(A + (size_t)row * K + kg * 8);
    }
    const short8* bp = reinterpret_cast<const short8*>(Wt + (size_t)(n0 + lrow) * K + kg * 8);

    f32x4 acc[4];
    #pragma unroll
    for (int mi = 0; mi < 4; ++mi) acc[mi] = {0.f, 0.f, 0.f, 0.f};

    #pragma unroll
    for (int k0 = 0; k0 < K; k0 += 32) {
        short8 bfr = bp[k0 >> 3];
        #pragma unroll
        for (int mi = 0; mi < 4; ++mi) {
            short8 afr = ap[mi][k0 >> 3];
            acc[mi] = __builtin_amdgcn_mfma_f32_16x16x32_bf16(afr, bfr, acc[mi], 0, 0, 0);
        }
    }

    #pragma unroll
    for (int mi = 0; mi < 4; ++mi) {
        int row_b = m_base + mi * 16 + kg * 4;
        #pragma unroll
        for (int r = 0; r < 4; ++r) {
            int row = row_b + r;
            if (row < M)
                C[(size_t)row * NC + n0 + lrow] = (unsigned short)f2bfbits(acc[mi][r]);
        }
    }
}

// ---------------- per-node score dots: s = h . a (h in bf16) ----------------

template <int F>
__global__ __launch_bounds__(256) void score_kernel(const __hip_bfloat16* __restrict__ h,
                                                    const float* __restrict__ a_src,
                                                    const float* __restrict__ a_dst,
                                                    float* __restrict__ ss,
                                                    float* __restrict__ sd, int N) {
    int node = blockIdx.x * (blockDim.x >> 6) + (threadIdx.x >> 6);
    int lane = threadIdx.x & 63;
    if (node >= N) return;
    float vs = 0.f, vd = 0.f;
    if (F == 128) {
        unsigned r = *reinterpret_cast<const unsigned*>(&h[(size_t)node * F + lane * 2]);
        float2 asv = *reinterpret_cast<const float2*>(&a_src[lane * 2]);
        float2 adv = *reinterpret_cast<const float2*>(&a_dst[lane * 2]);
        float h0 = bf_lo(r), h1 = bf_hi(r);
        vs = h0 * asv.x + h1 * asv.y;
        vd = h0 * adv.x + h1 * adv.y;
    } else {
        unsigned r = (unsigned)*reinterpret_cast<const unsigned short*>(&h[(size_t)node * F + lane]);
        float h0 = __uint_as_float(r << 16);
        vs = h0 * a_src[lane];
        vd = h0 * a_dst[lane];
    }
    #pragma unroll
    for (int off = 32; off; off >>= 1) {
        vs += __shfl_xor(vs, off, 64);
        vd += __shfl_xor(vd, off, 64);
    }
    if (lane == 0) { ss[node] = vs; sd[node] = vd; }
}

// ---------------- per-dst-node softmax + weighted gather (h in bf16) ----------------

template <int F, bool DO_ELU, bool OUT_BF16>
__global__ __launch_bounds__(256) void aggregate_kernel(
    const __hip_bfloat16* __restrict__ h, const float* __restrict__ ss,
    const float* __restrict__ sd, const int* __restrict__ row_start,
    const int* __restrict__ col_src, const float* __restrict__ bias,
    void* __restrict__ out_raw, int N) {
    constexpr int EPL = F / 64;  // elements per lane: 2 or 1
    int node = blockIdx.x * (blockDim.x >> 6) + (threadIdx.x >> 6);
    int lane = threadIdx.x & 63;
    if (node >= N) return;
    int rs = row_start[node], re = row_start[node + 1];
    int deg = re - rs;
    float sdn = sd[node];
    float acc[EPL];
    #pragma unroll
    for (int q = 0; q < EPL; ++q) acc[q] = 0.f;

    const unsigned* h32 = reinterpret_cast<const unsigned*>(h);
    const unsigned short* h16 = reinterpret_cast<const unsigned short*>(h);

    if (deg <= 64) {
        int s_l = 0;
        float e_l = -INFINITY;
        if (lane < deg) {
            s_l = col_src[rs + lane];
            e_l = leaky(ss[s_l] + sdn);
        }
        float m = e_l;
        #pragma unroll
        for (int off = 32; off; off >>= 1) m = fmaxf(m, __shfl_xor(m, off, 64));
        float w_l = (lane < deg) ? __expf(e_l - m) : 0.f;
        float den = w_l;
        #pragma unroll
        for (int off = 32; off; off >>= 1) den += __shfl_xor(den, off, 64);
        float alpha_l = w_l / den;

        int j = 0;
        for (; j + 4 <= deg; j += 4) {
            int s0 = __shfl(s_l, j, 64), s1 = __shfl(s_l, j + 1, 64);
            int s2 = __shfl(s_l, j + 2, 64), s3 = __shfl(s_l, j + 3, 64);
            float a0 = __shfl(alpha_l, j, 64), a1 = __shfl(alpha_l, j + 1, 64);
            float a2 = __shfl(alpha_l, j + 2, 64), a3 = __shfl(alpha_l, j + 3, 64);
            if (EPL == 2) {
                unsigned r0 = h32[(size_t)s0 * (F / 2) + lane];
                unsigned r1 = h32[(size_t)s1 * (F / 2) + lane];
                unsigned r2 = h32[(size_t)s2 * (F / 2) + lane];
                unsigned r3 = h32[(size_t)s3 * (F / 2) + lane];
                acc[0] += a0 * bf_lo(r0); acc[1] += a0 * bf_hi(r0);
                acc[0] += a1 * bf_lo(r1); acc[1] += a1 * bf_hi(r1);
                acc[0] += a2 * bf_lo(r2); acc[1] += a2 * bf_hi(r2);
                acc[0] += a3 * bf_lo(r3); acc[1] += a3 * bf_hi(r3);
            } else {
                unsigned r0 = h16[(size_t)s0 * F + lane];
                unsigned r1 = h16[(size_t)s1 * F + lane];
                unsigned r2 = h16[(size_t)s2 * F + lane];
                unsigned r3 = h16[(size_t)s3 * F + lane];
                acc[0] += a0 * __uint_as_float(r0 << 16);
                acc[0] += a1 * __uint_as_float(r1 << 16);
                acc[0] += a2 * __uint_as_float(r2 << 16);
                acc[0] += a3 * __uint_as_float(r3 << 16);
            }
        }
        for (; j < deg; ++j) {
            int s0 = __shfl(s_l, j, 64);
            float a0 = __shfl(alpha_l, j, 64);
            if (EPL == 2) {
                unsigned r0 = h32[(size_t)s0 * (F / 2) + lane];
                acc[0] += a0 * bf_lo(r0); acc[1] += a0 * bf_hi(r0);
            } else {
                unsigned r0 = h16[(size_t)s0 * F + lane];
                acc[0] += a0 * __uint_as_float(r0 << 16);
            }
        }
    } else {
        float m = -INFINITY;
        for (int j = rs + lane; j < re; j += 64) {
            float e = leaky(ss[col_src[j]] + sdn);
            m = fmaxf(m, e);
        }
        #pragma unroll
        for (int off = 32; off; off >>= 1) m = fmaxf(m, __shfl_xor(m, off, 64));
        float den = 0.f;
        for (int j = rs + lane; j < re; j += 64) {
            float e = leaky(ss[col_src[j]] + sdn);
            den += __expf(e - m);
        }
        #pragma unroll
        for (int off = 32; off; off >>= 1) den += __shfl_xor(den, off, 64);
        float inv_den = 1.f / den;
        for (int j = rs; j < re; ++j) {
            int s = col_src[j];
            float e = leaky(ss[s] + sdn);
            float alpha = __expf(e - m) * inv_den;
            if (EPL == 2) {
                unsigned r0 = h32[(size_t)s * (F / 2) + lane];
                acc[0] += alpha * bf_lo(r0); acc[1] += alpha * bf_hi(r0);
            } else {
                unsigned r0 = h16[(size_t)s * F + lane];
                acc[0] += alpha * __uint_as_float(r0 << 16);
            }
        }
    }

    if (EPL == 2) {
        float2 bv = *reinterpret_cast<const float2*>(&bias[lane * 2]);
        float v0 = acc[0] + bv.x, v1 = acc[1] + bv.y;
        if (DO_ELU) {
            v0 = v0 > 0.f ? v0 : (__expf(v0) - 1.f);
            v1 = v1 > 0.f ? v1 : (__expf(v1) - 1.f);
        }
        if (OUT_BF16) {
            unsigned pk = (unsigned)f2bfbits(v0) | ((unsigned)f2bfbits(v1) << 16);
            reinterpret_cast<unsigned*>(out_raw)[(size_t)node * (F / 2) + lane] = pk;
        } else {
            reinterpret_cast<float2*>(out_raw)[(size_t)node * (F / 2) + lane] =
                make_float2(v0, v1);
        }
    } else {
        float v0 = acc[0] + bias[lane];
        if (DO_ELU) v0 = v0 > 0.f ? v0 : (__expf(v0) - 1.f);
        reinterpret_cast<float*>(out_raw)[(size_t)node * F + lane] = v0;
    }
}

// ---------------- launch ----------------

extern "C" void kernel_launch(void* const* d_in, const int* in_sizes, int n_in,
                              void* d_out, int out_size, void* d_ws, size_t ws_size,
                              hipStream_t stream) {
    const float* x   = (const float*)d_in[0];
    const int*   ei  = (const int*)d_in[1];
    const float* W1  = (const float*)d_in[2];
    const float* a1s = (const float*)d_in[3];
    const float* a1d = (const float*)d_in[4];
    const float* b1  = (const float*)d_in[5];
    const float* W2  = (const float*)d_in[6];
    const float* a2s = (const float*)d_in[7];
    const float* a2d = (const float*)d_in[8];
    const float* b2  = (const float*)d_in[9];

    const int N    = in_sizes[0] / 256;  // IN_DIM = 256
    const int E    = in_sizes[1] / 2;
    const int Etot = E + N;
    const int* src = ei;
    const int* dst = ei + E;

    char* p = (char*)d_ws;
    auto carve = [&](size_t bytes) {
        char* r = p;
        p += (bytes + 255) & ~(size_t)255;
        return r;
    };
    unsigned short* h1  = (unsigned short*)carve((size_t)N * 128 * 2);
    unsigned short* h2  = (unsigned short*)carve((size_t)N * 64 * 2);
    unsigned short* x2b = (unsigned short*)carve((size_t)N * 128 * 2);
    unsigned short* wt1 = (unsigned short*)carve((size_t)128 * 256 * 2);
    unsigned short* wt2 = (unsigned short*)carve((size_t)64 * 128 * 2);
    float* s1s = (float*)carve((size_t)N * 4);
    float* s1d = (float*)carve((size_t)N * 4);
    float* s2s = (float*)carve((size_t)N * 4);
    float* s2d = (float*)carve((size_t)N * 4);
    int* counts = (int*)carve((size_t)N * 4);
    int* row_start = (int*)carve((size_t)(N + 1) * 4);
    int* col_src   = (int*)carve((size_t)Etot * 4);
    int* rank      = (int*)carve((size_t)Etot * 4);
    int* bsum      = (int*)carve((size_t)2048 * 4);

    hipMemsetAsync(counts, 0, (size_t)N * 4, stream);

    const int TB = 256;
    const int nb = (N + 1023) / 1024;

    wt_kernel<<<(128 * 256 + TB - 1) / TB, TB, 0, stream>>>(W1, wt1, 256, 128);
    wt_kernel<<<(64 * 128 + TB - 1) / TB, TB, 0, stream>>>(W2, wt2, 128, 64);

    hist_rank_kernel<<<(Etot + TB - 1) / TB, TB, 0, stream>>>(dst, E, Etot, counts, rank);
    scan_sum_kernel<<<nb, 256, 0, stream>>>(counts, N, bsum);
    scan_mid_kernel<<<1, 256, 0, stream>>>(bsum, nb, row_start + N);
    scan_out_kernel<<<nb, 256, 0, stream>>>(counts, N, bsum, row_start);
    fill_kernel<<<(Etot + TB - 1) / TB, TB, 0, stream>>>(src, dst, E, Etot,
                                                         row_start, rank, col_src);

    // layer 1
    mfma_gemm1<<<(N + 63) / 64, 256, 0, stream>>>(x, wt1, h1, N);
    score_kernel<128><<<(N + 3) / 4, 256, 0, stream>>>((const __hip_bfloat16*)h1,
                                                       a1s, a1d, s1s, s1d, N);
    aggregate_kernel<128, true, true><<<(N + 3) / 4, 256, 0, stream>>>(
        (const __hip_bfloat16*)h1, s1s, s1d, row_start, col_src, b1, x2b, N);

    // layer 2
    mfma_gemm2<<<(N + 63) / 64, 256, 0, stream>>>(x2b, wt2, h2, N);
    score_kernel<64><<<(N + 3) / 4, 256, 0, stream>>>((const __hip_bfloat16*)h2,
                                                      a2s, a2d, s2s, s2d, N);
    aggregate_kernel<64, false, false><<<(N + 3) / 4, 256, 0, stream>>>(
        (const __hip_bfloat16*)h2, s2s, s2d, row_start, col_src, b2, d_out, N);
}